// Round 15
// baseline (123.470 us; speedup 1.0000x reference)
//
#include <hip/hip_runtime.h>
#include <hip/hip_bf16.h>
#include <math.h>

#define NN 50000
#define NE 1000000
#define FIN 128
#define FOUT 64
#define NEG 0.2f

#define NB   2048     // dst-range buckets
#define DPB  25       // dsts per bucket; 2000*25 = 50000 exact
#define NBUSED 2000
#define TS   4096     // edges per sort tile (r13 showed 2048 regresses)
#define NT   245      // 244 full tiles + 576-edge tail (<= 256)
#define NTP  256      // padded row stride of transposed gofs
#define RCAP 1024     // per-bucket edge capacity (mean 500, sigma 22 -> 23s)
#define TILE_BLKS 245
#define GEMM_BLKS 391 // ceil(3125 strips / 8 waves)

using short8  = __attribute__((ext_vector_type(8))) short;
using floatx4 = __attribute__((ext_vector_type(4))) float;

static __device__ __forceinline__ short f2bf(float f) {
    __hip_bfloat16 h = __float2bfloat16(f);
    return *(short*)&h;
}

// Fused front kernel, 512 threads (r12-proven). Blocks [0,TILE_BLKS) =
// per-tile LDS counting-sort into 2048 buckets; blocks [TILE_BLKS,
// +GEMM_BLKS) = MFMA gemm. Disjoint data, concurrent execution.
// r11 lesson: integer LDS atomics only (fp32 LDS atomicAdd = CAS loop).
__global__ __launch_bounds__(512) void k_front(
    const float* __restrict__ x, const float* __restrict__ W,
    const float* __restrict__ a_src, const float* __restrict__ a_dst,
    const int* __restrict__ ei,
    __hip_bfloat16* __restrict__ Whb, float* __restrict__ s_src,
    float* __restrict__ s_dst,
    unsigned* __restrict__ bdata, unsigned short* __restrict__ gofs)
{
    __shared__ int cnt[NB];            // 8 KB (scan in-place -> cursor)
    __shared__ unsigned srt[TS];       // 16 KB
    __shared__ int wsum[8];

    const int tid  = threadIdx.x;
    const int lane = tid & 63;
    const int wv   = tid >> 6;

    if (blockIdx.x >= TILE_BLKS) {
        // ---------------- GEMM role ----------------
        // D = A(16x128)·B(128x64) via 4 K-steps x 4 N-tiles of
        // mfma_f32_16x16x32_bf16. A[m=lane&15][k=quad*8+j],
        // B[k=quad*8+j][n=lane&15], C: col=lane&15, row=quad*4+reg.
        const int col  = lane & 15;
        const int quad = lane >> 4;
        const int strip = (blockIdx.x - TILE_BLKS) * 8 + wv;
        if (strip >= NN / 16) return;          // 3125 strips
        const int row0 = strip * 16;

        short8 bfr[4][4];
        #pragma unroll
        for (int kk = 0; kk < 4; ++kk) {
            #pragma unroll
            for (int nt = 0; nt < 4; ++nt) {
                const float* wp = W + (kk * 32 + quad * 8) * FOUT + nt * 16 + col;
                #pragma unroll
                for (int j = 0; j < 8; ++j)
                    bfr[kk][nt][j] = f2bf(wp[j * FOUT]);
            }
        }

        floatx4 acc[4] = {{0.f,0.f,0.f,0.f},{0.f,0.f,0.f,0.f},
                          {0.f,0.f,0.f,0.f},{0.f,0.f,0.f,0.f}};

        const float* xrow = x + (size_t)(row0 + col) * FIN + quad * 8;
        #pragma unroll
        for (int kk = 0; kk < 4; ++kk) {
            const float4 u0 = *(const float4*)(xrow + kk * 32);
            const float4 u1 = *(const float4*)(xrow + kk * 32 + 4);
            short8 af;
            af[0] = f2bf(u0.x); af[1] = f2bf(u0.y);
            af[2] = f2bf(u0.z); af[3] = f2bf(u0.w);
            af[4] = f2bf(u1.x); af[5] = f2bf(u1.y);
            af[6] = f2bf(u1.z); af[7] = f2bf(u1.w);
            #pragma unroll
            for (int nt = 0; nt < 4; ++nt)
                acc[nt] = __builtin_amdgcn_mfma_f32_16x16x32_bf16(
                    af, bfr[kk][nt], acc[nt], 0, 0, 0);
        }

        const float av0 = a_src[col], av1 = a_src[16 + col];
        const float av2 = a_src[32 + col], av3 = a_src[48 + col];
        const float bv0 = a_dst[col], bv1 = a_dst[16 + col];
        const float bv2 = a_dst[32 + col], bv3 = a_dst[48 + col];

        float ps[4], pd[4];
        #pragma unroll
        for (int reg = 0; reg < 4; ++reg) {
            ps[reg] = acc[0][reg] * av0 + acc[1][reg] * av1
                    + acc[2][reg] * av2 + acc[3][reg] * av3;
            pd[reg] = acc[0][reg] * bv0 + acc[1][reg] * bv1
                    + acc[2][reg] * bv2 + acc[3][reg] * bv3;
        }

        #pragma unroll
        for (int nt = 0; nt < 4; ++nt)
            #pragma unroll
            for (int reg = 0; reg < 4; ++reg)
                Whb[(size_t)(row0 + quad * 4 + reg) * FOUT + nt * 16 + col] =
                    __float2bfloat16(acc[nt][reg]);

        #pragma unroll
        for (int off = 1; off < 16; off <<= 1) {
            #pragma unroll
            for (int reg = 0; reg < 4; ++reg) {
                ps[reg] += __shfl_xor(ps[reg], off);
                pd[reg] += __shfl_xor(pd[reg], off);
            }
        }
        if (col == 0) {
            #pragma unroll
            for (int reg = 0; reg < 4; ++reg) {
                s_src[row0 + quad * 4 + reg] = ps[reg];
                s_dst[row0 + quad * 4 + reg] = pd[reg];
            }
        }
        return;
    }

    // ---------------- TILESORT role ----------------
    const int tile = blockIdx.x;
    const int base = tile * TS;
    const int tcnt = (NE - base < TS) ? (NE - base) : TS;

    for (int i = tid; i < NB; i += 512) cnt[i] = 0;
    __syncthreads();

    unsigned pk[8];
    #pragma unroll
    for (int j = 0; j < 8; ++j) {
        const int i = j * 512 + tid;
        if (i < tcnt) {
            const int e = base + i;
            const unsigned s = (unsigned)__builtin_nontemporal_load(ei + e);
            const unsigned d = (unsigned)__builtin_nontemporal_load(ei + NE + e);
            pk[j] = (s << 16) | d;
            atomicAdd(&cnt[d / DPB], 1);
        } else pk[j] = 0xFFFFFFFFu;
    }
    __syncthreads();

    // exclusive scan of cnt[0..2048): 4 bins/thread; offsets written back
    // IN-PLACE into cnt (becomes the scatter cursor).
    {
        const int i0 = tid * 4;
        const int v0 = cnt[i0], v1 = cnt[i0 + 1];
        const int v2 = cnt[i0 + 2], v3 = cnt[i0 + 3];
        const int s = v0 + v1 + v2 + v3;
        int inc = s;
        #pragma unroll
        for (int off = 1; off < 64; off <<= 1) {
            const int t = __shfl_up(inc, off);
            if (lane >= off) inc += t;
        }
        if (lane == 63) wsum[wv] = inc;
        __syncthreads();
        int wb = 0;
        #pragma unroll
        for (int w = 0; w < 7; ++w) if (w < wv) wb += wsum[w];
        const int excl = wb + inc - s;
        cnt[i0]     = excl;
        cnt[i0 + 1] = excl + v0;
        cnt[i0 + 2] = excl + v0 + v1;
        cnt[i0 + 3] = excl + v0 + v1 + v2;
        ushort4 g;
        g.x = (unsigned short)excl;
        g.y = (unsigned short)(excl + v0);
        g.z = (unsigned short)(excl + v0 + v1);
        g.w = (unsigned short)(excl + v0 + v1 + v2);
        *(ushort4*)(gofs + (size_t)tile * NB + i0) = g;
    }
    __syncthreads();

    #pragma unroll
    for (int j = 0; j < 8; ++j) {
        if (pk[j] != 0xFFFFFFFFu) {
            const int b = (int)(pk[j] & 0xffffu) / DPB;
            const int pos = atomicAdd(&cnt[b], 1);
            srt[pos] = pk[j];
        }
    }
    __syncthreads();

    for (int i = tid; i < tcnt; i += 512)
        bdata[base + i] = srt[i];
}

// Transpose gofs[t][b] (245x2048 ushort) -> gofs_t[b][t] (2048 rows, stride
// NTP=256 ushort). 512 blocks of 256 threads.
__global__ __launch_bounds__(256) void k_transp(
    const unsigned short* __restrict__ gofs, unsigned short* __restrict__ gofs_t)
{
    __shared__ unsigned short tb[32][33];
    const int bi = blockIdx.x & 63;    // 2048/32 bucket tiles
    const int ti = blockIdx.x >> 6;    // 8 t-tiles cover 256 >= NT
    const int r = threadIdx.x >> 5;    // 0..7
    const int c = threadIdx.x & 31;
    for (int rr = r; rr < 32; rr += 8) {
        const int t = ti * 32 + rr;
        tb[rr][c] = (t < NT) ? gofs[(size_t)t * NB + bi * 32 + c] : 0;
    }
    __syncthreads();
    for (int rr = r; rr < 32; rr += 8) {
        const int b = bi * 32 + rr;
        gofs_t[(size_t)b * NTP + ti * 32 + c] = tb[c][rr];
    }
}

// Per-bucket gather (25 dsts, ~500 edges), 256 threads. 4-way lane-split
// gather: quarter q = lane>>4 handles edge i+q; 16 lanes/row load uint2
// (4 bf16 features) -> ONE wave-load covers FOUR Whb rows (512 B), half
// the load instructions of the r12 2-way split. Cross-quarter combine via
// shfl_xor(16)+shfl_xor(32); quarter 0 stores full float4 rows.
__global__ __launch_bounds__(256) void k_sortgather(
    const unsigned short* __restrict__ gofs_t, const unsigned* __restrict__ bdata,
    const float* __restrict__ s_src, const float* __restrict__ s_dst,
    const __hip_bfloat16* __restrict__ Whb, float* __restrict__ out)
{
    __shared__ unsigned raw[RCAP];     // 4 KB
    __shared__ uint2 pes[RCAP];        // 8 KB  {packed, ev bits}
    __shared__ float sdl[32];
    __shared__ int cnt[32];
    __shared__ int ofs2[33];
    __shared__ int cur[32];
    __shared__ int wsum[4];

    const int b = (blockIdx.x & 7) * 250 + (blockIdx.x >> 3);  // XCD swizzle
    const int tid = threadIdx.x;
    const int lane = tid & 63;
    const int wv = tid >> 6;
    const int d0 = b * DPB;

    if (tid < 32) {
        cnt[tid] = 0;
        sdl[tid] = (tid < DPB) ? s_dst[d0 + tid] : 0.f;
    }

    // tile-segment lengths from coalesced transposed-gofs rows b, b+1
    int c = 0, o = 0;
    if (tid < NT) {
        o = (int)gofs_t[(size_t)b * NTP + tid];
        const int tc = (tid < NT - 1) ? TS : (NE - (NT - 1) * TS);
        const int nx = (b + 1 < NB) ? (int)gofs_t[(size_t)(b + 1) * NTP + tid] : tc;
        c = nx - o;
    }
    int inc = c;
    #pragma unroll
    for (int off = 1; off < 64; off <<= 1) {
        const int t = __shfl_up(inc, off);
        if (lane >= off) inc += t;
    }
    if (lane == 63) wsum[wv] = inc;
    __syncthreads();
    int wb = 0;
    #pragma unroll
    for (int w = 0; w < 3; ++w) if (w < wv) wb += wsum[w];
    const int segbase = wb + inc - c;
    int tot = wsum[0] + wsum[1] + wsum[2] + wsum[3];
    if (tot > RCAP) tot = RCAP;        // defensive (23-sigma headroom)

    for (int k = 0; k < c; ++k) {
        const int p = segbase + k;
        if (p < RCAP) raw[p] = bdata[(size_t)tid * TS + o + k];
    }
    __syncthreads();

    for (int i = tid; i < tot; i += 256)
        atomicAdd(&cnt[(int)(raw[i] & 0xffffu) - d0], 1);
    __syncthreads();

    if (tid < 32) {
        const int cc = (tid < DPB) ? cnt[tid] : 0;
        int in2 = cc;
        #pragma unroll
        for (int off = 1; off < 32; off <<= 1) {
            const int t = __shfl_up(in2, off);
            if (tid >= off) in2 += t;
        }
        ofs2[tid + 1] = in2;
        if (tid == 0) ofs2[0] = 0;
        cur[tid] = in2 - cc;
    }
    __syncthreads();

    // LDS scatter into dst order + fused ev compute -> uint2
    for (int i = tid; i < tot; i += 256) {
        const unsigned p = raw[i];
        const int j = (int)(p & 0xffffu) - d0;
        const int pos = atomicAdd(&cur[j], 1);
        float v = s_src[p >> 16] + sdl[j];
        v = (v > 0.f) ? v : NEG * v;
        pes[pos] = make_uint2(p, __float_as_uint(__expf(v)));
    }
    __syncthreads();

    // gather: wave = dst; quarter q = edge slot, l4 = feature-quad index
    const int q  = lane >> 4;          // 0..3: edge i+q
    const int l4 = lane & 15;          // features 4*l4 .. 4*l4+3
    for (int j = wv; j < DPB; j += 4) {
        const int d = d0 + j;
        const int beg = ofs2[j];
        const int end = ofs2[j + 1];
        float a0 = 0.f, a1 = 0.f, a2 = 0.f, a3 = 0.f, dacc = 0.f;
        int i = beg;
        for (; i + 16 <= end; i += 16) {
            #pragma unroll
            for (int k = 0; k < 4; ++k) {
                const uint2 pe = pes[i + 4 * k + q];
                const float ev = __uint_as_float(pe.y);
                const uint2 u = ((const uint2*)(Whb +
                        (size_t)(pe.x >> 16) * FOUT))[l4];
                a0 = fmaf(ev, __uint_as_float(u.x << 16), a0);
                a1 = fmaf(ev, __uint_as_float(u.x & 0xffff0000u), a1);
                a2 = fmaf(ev, __uint_as_float(u.y << 16), a2);
                a3 = fmaf(ev, __uint_as_float(u.y & 0xffff0000u), a3);
                dacc += ev;
            }
        }
        for (; i + 4 <= end; i += 4) {
            const uint2 pe = pes[i + q];
            const float ev = __uint_as_float(pe.y);
            const uint2 u = ((const uint2*)(Whb +
                    (size_t)(pe.x >> 16) * FOUT))[l4];
            a0 = fmaf(ev, __uint_as_float(u.x << 16), a0);
            a1 = fmaf(ev, __uint_as_float(u.x & 0xffff0000u), a1);
            a2 = fmaf(ev, __uint_as_float(u.y << 16), a2);
            a3 = fmaf(ev, __uint_as_float(u.y & 0xffff0000u), a3);
            dacc += ev;
        }
        if (i + q < end) {             // tail: quarters q < remaining
            const uint2 pe = pes[i + q];
            const float ev = __uint_as_float(pe.y);
            const uint2 u = ((const uint2*)(Whb +
                    (size_t)(pe.x >> 16) * FOUT))[l4];
            a0 = fmaf(ev, __uint_as_float(u.x << 16), a0);
            a1 = fmaf(ev, __uint_as_float(u.x & 0xffff0000u), a1);
            a2 = fmaf(ev, __uint_as_float(u.y << 16), a2);
            a3 = fmaf(ev, __uint_as_float(u.y & 0xffff0000u), a3);
            dacc += ev;
        }
        a0 += __shfl_xor(a0, 16); a0 += __shfl_xor(a0, 32);
        a1 += __shfl_xor(a1, 16); a1 += __shfl_xor(a1, 32);
        a2 += __shfl_xor(a2, 16); a2 += __shfl_xor(a2, 32);
        a3 += __shfl_xor(a3, 16); a3 += __shfl_xor(a3, 32);
        dacc += __shfl_xor(dacc, 16); dacc += __shfl_xor(dacc, 32);
        if (q == 0) {
            const float rd = 1.f / (dacc + 1e-16f);
            float r0 = a0 * rd, r1 = a1 * rd, r2 = a2 * rd, r3 = a3 * rd;
            r0 = (r0 > 0.f) ? r0 : expm1f(r0);
            r1 = (r1 > 0.f) ? r1 : expm1f(r1);
            r2 = (r2 > 0.f) ? r2 : expm1f(r2);
            r3 = (r3 > 0.f) ? r3 : expm1f(r3);
            ((float4*)(out + (size_t)d * FOUT))[l4] =
                make_float4(r0, r1, r2, r3);
        }
    }
}

extern "C" void kernel_launch(void* const* d_in, const int* in_sizes, int n_in,
                              void* d_out, int out_size, void* d_ws, size_t ws_size,
                              hipStream_t stream)
{
    const float* x     = (const float*)d_in[0];
    const int*   ei    = (const int*)d_in[1];   // [2,E]: src = ei[0..E), dst = ei[E..2E)
    const float* W     = (const float*)d_in[2];
    const float* a_src = (const float*)d_in[3];
    const float* a_dst = (const float*)d_in[4];
    float* out = (float*)d_out;

    // Workspace: Whb 6.4 MB | s_src 200 KB | s_dst 200 KB | gofs 1 MB (u16)
    // | gofs_t 1 MB (u16) | bdata 4 MB -> ~12.8 MB. No memsets needed.
    float* ws    = (float*)d_ws;
    __hip_bfloat16* Whb = (__hip_bfloat16*)ws;
    float* s_src = ws + (size_t)NN * FOUT / 2;
    float* s_dst = s_src + NN;
    unsigned short* gofs   = (unsigned short*)(s_dst + NN);
    unsigned short* gofs_t = gofs + (size_t)NT * NB + 64;   // 4B-align slack
    unsigned* bdata = (unsigned*)(gofs_t + (size_t)NB * NTP);

    k_front<<<TILE_BLKS + GEMM_BLKS, 512, 0, stream>>>(
        x, W, a_src, a_dst, ei, Whb, s_src, s_dst, bdata, gofs);
    k_transp<<<512, 256, 0, stream>>>(gofs, gofs_t);
    k_sortgather<<<NBUSED, 256, 0, stream>>>(gofs_t, bdata, s_src, s_dst,
                                             Whb, out);
}

// Round 16
// 122.300 us; speedup vs baseline: 1.0096x; 1.0096x over previous
//
#include <hip/hip_runtime.h>
#include <hip/hip_bf16.h>
#include <math.h>

#define NN 50000
#define NE 1000000
#define FIN 128
#define FOUT 64
#define NEG 0.2f

#define NB   2048     // dst-range buckets
#define DPB  25       // dsts per bucket; 2000*25 = 50000 exact
#define NBUSED 2000
#define TS   4096     // edges per sort tile
#define NT   245      // 244 full tiles + 576-edge tail (<= 256)
#define NTP  256      // padded row stride of transposed gofs
#define RCAP 1024     // per-bucket edge capacity (mean 500, sigma 22 -> 23s)
#define TILE_BLKS 245
#define GEMM_BLKS 391 // ceil(3125 strips / 8 waves)

using short8  = __attribute__((ext_vector_type(8))) short;
using floatx4 = __attribute__((ext_vector_type(4))) float;

static __device__ __forceinline__ short f2bf(float f) {
    __hip_bfloat16 h = __float2bfloat16(f);
    return *(short*)&h;
}

// Fused front kernel, 512 threads (r8/r12-proven best). Blocks
// [0,TILE_BLKS) = per-tile LDS counting-sort into 2048 buckets; blocks
// [TILE_BLKS,+GEMM_BLKS) = MFMA gemm. Disjoint data, concurrent execution.
// r11 lesson: integer LDS atomics only — fp32 LDS atomicAdd is a CAS loop
// on gfx950 and serializes catastrophically (122 -> 453 us).
__global__ __launch_bounds__(512) void k_front(
    const float* __restrict__ x, const float* __restrict__ W,
    const float* __restrict__ a_src, const float* __restrict__ a_dst,
    const int* __restrict__ ei,
    __hip_bfloat16* __restrict__ Whb, float* __restrict__ s_src,
    float* __restrict__ s_dst,
    unsigned* __restrict__ bdata, int* __restrict__ gofs)
{
    __shared__ int cnt[NB];            // 8 KB
    __shared__ int cur[NB];            // 8 KB
    __shared__ unsigned srt[TS];       // 16 KB
    __shared__ int wsum[8];

    const int tid  = threadIdx.x;
    const int lane = tid & 63;
    const int wv   = tid >> 6;

    if (blockIdx.x >= TILE_BLKS) {
        // ---------------- GEMM role ----------------
        // D = A(16x128)·B(128x64) via 4 K-steps x 4 N-tiles of
        // mfma_f32_16x16x32_bf16. A[m=lane&15][k=quad*8+j],
        // B[k=quad*8+j][n=lane&15], C: col=lane&15, row=quad*4+reg.
        const int col  = lane & 15;
        const int quad = lane >> 4;
        const int strip = (blockIdx.x - TILE_BLKS) * 8 + wv;
        if (strip >= NN / 16) return;          // 3125 strips
        const int row0 = strip * 16;

        short8 bfr[4][4];
        #pragma unroll
        for (int kk = 0; kk < 4; ++kk) {
            #pragma unroll
            for (int nt = 0; nt < 4; ++nt) {
                const float* wp = W + (kk * 32 + quad * 8) * FOUT + nt * 16 + col;
                #pragma unroll
                for (int j = 0; j < 8; ++j)
                    bfr[kk][nt][j] = f2bf(wp[j * FOUT]);
            }
        }

        floatx4 acc[4] = {{0.f,0.f,0.f,0.f},{0.f,0.f,0.f,0.f},
                          {0.f,0.f,0.f,0.f},{0.f,0.f,0.f,0.f}};

        const float* xrow = x + (size_t)(row0 + col) * FIN + quad * 8;
        #pragma unroll
        for (int kk = 0; kk < 4; ++kk) {
            const float4 u0 = *(const float4*)(xrow + kk * 32);
            const float4 u1 = *(const float4*)(xrow + kk * 32 + 4);
            short8 af;
            af[0] = f2bf(u0.x); af[1] = f2bf(u0.y);
            af[2] = f2bf(u0.z); af[3] = f2bf(u0.w);
            af[4] = f2bf(u1.x); af[5] = f2bf(u1.y);
            af[6] = f2bf(u1.z); af[7] = f2bf(u1.w);
            #pragma unroll
            for (int nt = 0; nt < 4; ++nt)
                acc[nt] = __builtin_amdgcn_mfma_f32_16x16x32_bf16(
                    af, bfr[kk][nt], acc[nt], 0, 0, 0);
        }

        const float av0 = a_src[col], av1 = a_src[16 + col];
        const float av2 = a_src[32 + col], av3 = a_src[48 + col];
        const float bv0 = a_dst[col], bv1 = a_dst[16 + col];
        const float bv2 = a_dst[32 + col], bv3 = a_dst[48 + col];

        float ps[4], pd[4];
        #pragma unroll
        for (int reg = 0; reg < 4; ++reg) {
            ps[reg] = acc[0][reg] * av0 + acc[1][reg] * av1
                    + acc[2][reg] * av2 + acc[3][reg] * av3;
            pd[reg] = acc[0][reg] * bv0 + acc[1][reg] * bv1
                    + acc[2][reg] * bv2 + acc[3][reg] * bv3;
        }

        #pragma unroll
        for (int nt = 0; nt < 4; ++nt)
            #pragma unroll
            for (int reg = 0; reg < 4; ++reg)
                Whb[(size_t)(row0 + quad * 4 + reg) * FOUT + nt * 16 + col] =
                    __float2bfloat16(acc[nt][reg]);

        #pragma unroll
        for (int off = 1; off < 16; off <<= 1) {
            #pragma unroll
            for (int reg = 0; reg < 4; ++reg) {
                ps[reg] += __shfl_xor(ps[reg], off);
                pd[reg] += __shfl_xor(pd[reg], off);
            }
        }
        if (col == 0) {
            #pragma unroll
            for (int reg = 0; reg < 4; ++reg) {
                s_src[row0 + quad * 4 + reg] = ps[reg];
                s_dst[row0 + quad * 4 + reg] = pd[reg];
            }
        }
        return;
    }

    // ---------------- TILESORT role ----------------
    const int tile = blockIdx.x;
    const int base = tile * TS;
    const int tcnt = (NE - base < TS) ? (NE - base) : TS;

    for (int i = tid; i < NB; i += 512) cnt[i] = 0;
    __syncthreads();

    unsigned pk[8];
    #pragma unroll
    for (int j = 0; j < 8; ++j) {
        const int i = j * 512 + tid;
        if (i < tcnt) {
            const int e = base + i;
            const unsigned s = (unsigned)__builtin_nontemporal_load(ei + e);
            const unsigned d = (unsigned)__builtin_nontemporal_load(ei + NE + e);
            pk[j] = (s << 16) | d;
            atomicAdd(&cnt[d / DPB], 1);
        } else pk[j] = 0xFFFFFFFFu;
    }
    __syncthreads();

    // exclusive scan of cnt[0..2048): 4 bins/thread, wave scans + combine
    {
        const int i0 = tid * 4;
        const int v0 = cnt[i0], v1 = cnt[i0 + 1];
        const int v2 = cnt[i0 + 2], v3 = cnt[i0 + 3];
        const int s = v0 + v1 + v2 + v3;
        int inc = s;
        #pragma unroll
        for (int off = 1; off < 64; off <<= 1) {
            const int t = __shfl_up(inc, off);
            if (lane >= off) inc += t;
        }
        if (lane == 63) wsum[wv] = inc;
        __syncthreads();
        int wb = 0;
        #pragma unroll
        for (int w = 0; w < 7; ++w) if (w < wv) wb += wsum[w];
        const int excl = wb + inc - s;
        cur[i0]     = excl;
        cur[i0 + 1] = excl + v0;
        cur[i0 + 2] = excl + v0 + v1;
        cur[i0 + 3] = excl + v0 + v1 + v2;
        *(int4*)(gofs + (size_t)tile * NB + i0) =
            make_int4(excl, excl + v0, excl + v0 + v1, excl + v0 + v1 + v2);
    }
    __syncthreads();

    #pragma unroll
    for (int j = 0; j < 8; ++j) {
        if (pk[j] != 0xFFFFFFFFu) {
            const int b = (int)(pk[j] & 0xffffu) / DPB;
            const int pos = atomicAdd(&cur[b], 1);
            srt[pos] = pk[j];
        }
    }
    __syncthreads();

    for (int i = tid; i < tcnt; i += 512)
        bdata[base + i] = srt[i];
}

// Transpose gofs[t][b] -> gofs_t[b][t] (row stride NTP=256, padded).
__global__ __launch_bounds__(256) void k_transp(
    const int* __restrict__ gofs, int* __restrict__ gofs_t)
{
    __shared__ int tb[32][33];
    const int bi = blockIdx.x & 63;    // 2048/32 bucket tiles
    const int ti = blockIdx.x >> 6;    // 8 t-tiles cover 256 >= NT
    const int r = threadIdx.x >> 5;    // 0..7
    const int c = threadIdx.x & 31;
    for (int rr = r; rr < 32; rr += 8) {
        const int t = ti * 32 + rr;
        tb[rr][c] = (t < NT) ? gofs[(size_t)t * NB + bi * 32 + c] : 0;
    }
    __syncthreads();
    for (int rr = r; rr < 32; rr += 8) {
        const int b = bi * 32 + rr;
        gofs_t[(size_t)b * NTP + ti * 32 + c] = tb[c][rr];
    }
}

// Per-bucket gather (25 dsts, ~500 edges). Lane-split gather: lanes 0-31 =
// edge i, lanes 32-63 = edge i+1; each lane loads one uint (2 bf16
// features) so one wave-load covers TWO Whb rows (256 B). Scatter emits
// uint2{packed, ev_bits} (fused ev = exp(lrelu(s_src+s_dst))); halves
// combined via shfl_xor(32). Normalize + ELU fused; float2 stores.
__global__ __launch_bounds__(256) void k_sortgather(
    const int* __restrict__ gofs_t, const unsigned* __restrict__ bdata,
    const float* __restrict__ s_src, const float* __restrict__ s_dst,
    const __hip_bfloat16* __restrict__ Whb, float* __restrict__ out)
{
    __shared__ unsigned raw[RCAP];     // 4 KB
    __shared__ uint2 pes[RCAP];        // 8 KB  {packed, ev bits}
    __shared__ float sdl[32];
    __shared__ int cnt[32];
    __shared__ int ofs2[33];
    __shared__ int cur[32];
    __shared__ int wsum[4];

    const int b = (blockIdx.x & 7) * 250 + (blockIdx.x >> 3);  // XCD swizzle
    const int tid = threadIdx.x;
    const int lane = tid & 63;
    const int wv = tid >> 6;
    const int d0 = b * DPB;

    if (tid < 32) {
        cnt[tid] = 0;
        sdl[tid] = (tid < DPB) ? s_dst[d0 + tid] : 0.f;
    }

    // tile-segment lengths from coalesced transposed-gofs rows b, b+1
    int c = 0, o = 0;
    if (tid < NT) {
        o = gofs_t[(size_t)b * NTP + tid];
        c = gofs_t[(size_t)(b + 1) * NTP + tid] - o;
    }
    int inc = c;
    #pragma unroll
    for (int off = 1; off < 64; off <<= 1) {
        const int t = __shfl_up(inc, off);
        if (lane >= off) inc += t;
    }
    if (lane == 63) wsum[wv] = inc;
    __syncthreads();
    int wb = 0;
    #pragma unroll
    for (int w = 0; w < 3; ++w) if (w < wv) wb += wsum[w];
    const int segbase = wb + inc - c;
    int tot = wsum[0] + wsum[1] + wsum[2] + wsum[3];
    if (tot > RCAP) tot = RCAP;        // defensive (23-sigma headroom)

    for (int k = 0; k < c; ++k) {
        const int p = segbase + k;
        if (p < RCAP) raw[p] = bdata[(size_t)tid * TS + o + k];
    }
    __syncthreads();

    for (int i = tid; i < tot; i += 256)
        atomicAdd(&cnt[(int)(raw[i] & 0xffffu) - d0], 1);
    __syncthreads();

    if (tid < 32) {
        const int cc = (tid < DPB) ? cnt[tid] : 0;
        int in2 = cc;
        #pragma unroll
        for (int off = 1; off < 32; off <<= 1) {
            const int t = __shfl_up(in2, off);
            if (tid >= off) in2 += t;
        }
        ofs2[tid + 1] = in2;
        if (tid == 0) ofs2[0] = 0;
        cur[tid] = in2 - cc;
    }
    __syncthreads();

    // LDS scatter into dst order + fused ev compute -> uint2
    for (int i = tid; i < tot; i += 256) {
        const unsigned p = raw[i];
        const int j = (int)(p & 0xffffu) - d0;
        const int pos = atomicAdd(&cur[j], 1);
        float v = s_src[p >> 16] + sdl[j];
        v = (v > 0.f) ? v : NEG * v;
        pes[pos] = make_uint2(p, __float_as_uint(__expf(v)));
    }
    __syncthreads();

    // gather: wave = dst; half h = edge parity, l5 = feature pair index
    const int h  = lane >> 5;          // 0: even edge, 1: odd edge
    const int l5 = lane & 31;          // features 2*l5, 2*l5+1
    for (int j = wv; j < DPB; j += 4) {
        const int d = d0 + j;
        const int beg = ofs2[j];
        const int end = ofs2[j + 1];
        float a0 = 0.f, a1 = 0.f, dacc = 0.f;
        int i = beg;
        for (; i + 8 <= end; i += 8) {
            #pragma unroll
            for (int k = 0; k < 4; ++k) {
                const uint2 q = pes[i + 2 * k + h];
                const float ev = __uint_as_float(q.y);
                const unsigned u = ((const unsigned*)(Whb +
                        (size_t)(q.x >> 16) * FOUT))[l5];
                const float f0 = __uint_as_float(u << 16);
                const float f1 = __uint_as_float(u & 0xffff0000u);
                a0 = fmaf(ev, f0, a0);
                a1 = fmaf(ev, f1, a1);
                dacc += ev;
            }
        }
        for (; i + 2 <= end; i += 2) {
            const uint2 q = pes[i + h];
            const float ev = __uint_as_float(q.y);
            const unsigned u = ((const unsigned*)(Whb +
                    (size_t)(q.x >> 16) * FOUT))[l5];
            a0 = fmaf(ev, __uint_as_float(u << 16), a0);
            a1 = fmaf(ev, __uint_as_float(u & 0xffff0000u), a1);
            dacc += ev;
        }
        if (i < end && h == 0) {       // odd tail: half 0 only
            const uint2 q = pes[i];
            const float ev = __uint_as_float(q.y);
            const unsigned u = ((const unsigned*)(Whb +
                    (size_t)(q.x >> 16) * FOUT))[l5];
            a0 = fmaf(ev, __uint_as_float(u << 16), a0);
            a1 = fmaf(ev, __uint_as_float(u & 0xffff0000u), a1);
            dacc += ev;
        }
        // combine halves
        a0 += __shfl_xor(a0, 32);
        a1 += __shfl_xor(a1, 32);
        dacc += __shfl_xor(dacc, 32);
        if (h == 0) {
            const float rd = 1.f / (dacc + 1e-16f);
            float r0 = a0 * rd, r1 = a1 * rd;
            r0 = (r0 > 0.f) ? r0 : expm1f(r0);
            r1 = (r1 > 0.f) ? r1 : expm1f(r1);
            ((float2*)(out + (size_t)d * FOUT))[l5] = make_float2(r0, r1);
        }
    }
}

extern "C" void kernel_launch(void* const* d_in, const int* in_sizes, int n_in,
                              void* d_out, int out_size, void* d_ws, size_t ws_size,
                              hipStream_t stream)
{
    const float* x     = (const float*)d_in[0];
    const int*   ei    = (const int*)d_in[1];   // [2,E]: src = ei[0..E), dst = ei[E..2E)
    const float* W     = (const float*)d_in[2];
    const float* a_src = (const float*)d_in[3];
    const float* a_dst = (const float*)d_in[4];
    float* out = (float*)d_out;

    // Workspace: Whb 6.4 MB | s_src 200 KB | s_dst 200 KB | gofs 2 MB |
    // gofs_t 2 MB | bdata 4 MB -> ~14.8 MB. No memsets needed.
    float* ws    = (float*)d_ws;
    __hip_bfloat16* Whb = (__hip_bfloat16*)ws;
    float* s_src = ws + (size_t)NN * FOUT / 2;
    float* s_dst = s_src + NN;
    int*   gofs  = (int*)(s_dst + NN);
    int*   gofs_t = gofs + (size_t)NT * NB;
    unsigned* bdata = (unsigned*)(gofs_t + (size_t)NB * NTP);

    k_front<<<TILE_BLKS + GEMM_BLKS, 512, 0, stream>>>(
        x, W, a_src, a_dst, ei, Whb, s_src, s_dst, bdata, gofs);
    k_transp<<<512, 256, 0, stream>>>(gofs, gofs_t);
    k_sortgather<<<NBUSED, 256, 0, stream>>>(gofs_t, bdata, s_src, s_dst,
                                             Whb, out);
}